// Round 6
// baseline (168.000 us; speedup 1.0000x reference)
//
#include <hip/hip_runtime.h>

#define T_LEN 512

typedef float v2f __attribute__((ext_vector_type(2)));

// DPP self-permute: dst[lane] = src[perm(lane)] — all lanes active, no bound_ctrl.
template <int CTRL>
__device__ __forceinline__ float dppf(float v) {
    return __int_as_float(__builtin_amdgcn_update_dpp(
        __float_as_int(v), __float_as_int(v), CTRL, 0xF, 0xF, false));
}
#define DPP_X1 0xB1   // quad_perm [1,0,3,2] : lane^1  (exact)
#define DPP_X2 0x4E   // quad_perm [2,3,0,1] : lane^2  (exact)
#define DPP_X8 0x128  // row_ror:8 : lane^8  (rotate by half-row = xor, direction-proof)

// One wave = 2 batch elements. Hidden unit h on lane bits {0,1,3,4,5}; sub-batch
// on bit 2 (untouched by every exchange). h_t is register-resident; per step a
// pure-XOR butterfly all-gather (shfl_xor 16/32/48 = 3 parallel ds_bpermute off
// hn, then DPP ^8/^2/^1) delivers all 32 h-values. All stages are relative-XOR,
// so gathered slot s at lane l holds h[h_own XOR s] -> weights loaded permuted:
// w2[s] = W_row[h ^ s]. No LDS on the recurrence path (round-4 chain was ~400cyc
// of ds_write->ds_read; this chain is ~120cyc).
__global__ void __launch_bounds__(256) __attribute__((amdgpu_waves_per_eu(2, 2)))
rnn_fused(
    const float* __restrict__ x,
    const float* __restrict__ W_ih,
    const float* __restrict__ W_hh,
    const float* __restrict__ b_ih,
    const float* __restrict__ b_hh,
    const float* __restrict__ fc_w,
    const float* __restrict__ fc_b,
    float* __restrict__ out)
{
    __shared__ __align__(16) float xbuf[4][2][34];  // x chunk broadcast (off critical path)

    const int tid  = threadIdx.x;
    const int wv   = tid >> 6;
    const int lane = tid & 63;
    const int sub  = (lane >> 2) & 1;                 // batch within wave (lane bit 2)
    const int h    = (lane & 3) | ((lane >> 1) & 28); // hidden unit: bits {0,1,3,4,5}
    const int b    = (blockIdx.x << 3) + (wv << 1) + sub;

    // Slot s holds h[h ^ s] -> weight for slot s is W_hh[h][h ^ s].
    const float* wr = W_hh + h * 32;
    v2f w2[16];
#pragma unroll
    for (int m = 0; m < 16; ++m) {
        w2[m].x = wr[h ^ (2 * m)];
        w2[m].y = wr[h ^ (2 * m + 1)];
    }

    const float wih  = W_ih[h];
    const float bias = b_ih[h] + b_hh[h];
    const float* xrow = x + (size_t)b * T_LEN;

    float* xw = &xbuf[wv][sub][0];
    xw[h] = xrow[h];            // stage x chunk 0 (each lane writes its sub's slot h)

    float hn = 0.0f;            // h_t[own unit] — register-resident recurrence state
#pragma unroll 1
    for (int c = 0; c < T_LEN / 32; ++c) {
        // anti-AGPR insurance (emits nothing if weights stayed in arch VGPRs)
        asm volatile("" : "+v"(w2[0]), "+v"(w2[1]), "+v"(w2[2]), "+v"(w2[3]),
                          "+v"(w2[4]), "+v"(w2[5]), "+v"(w2[6]), "+v"(w2[7]));
        asm volatile("" : "+v"(w2[8]), "+v"(w2[9]), "+v"(w2[10]), "+v"(w2[11]),
                          "+v"(w2[12]), "+v"(w2[13]), "+v"(w2[14]), "+v"(w2[15]));
        float xn = 0.0f;
        const bool more = (c < T_LEN / 32 - 1);
        if (more) xn = xrow[(c + 1) * 32 + h];       // prefetch next x chunk
#pragma unroll
        for (int tc = 0; tc < 32; ++tc) {
            const float xt = xw[tc];                 // per-sub uniform broadcast read
            const float xp = __builtin_fmaf(xt, wih, bias);

            // ---- all-gather: slot index s = (f5,f4,f3,f1,f0) flip pattern ----
            const float s16_0 = hn;                       // no flip
            const float s16_1 = __shfl_xor(hn, 16, 64);   // f4
            const float s16_2 = __shfl_xor(hn, 32, 64);   // f5
            const float s16_3 = __shfl_xor(hn, 48, 64);   // f5^f4
            float s8[8];
            s8[0] = s16_0;  s8[1] = dppf<DPP_X8>(s16_0);  // +f3
            s8[2] = s16_1;  s8[3] = dppf<DPP_X8>(s16_1);
            s8[4] = s16_2;  s8[5] = dppf<DPP_X8>(s16_2);
            s8[6] = s16_3;  s8[7] = dppf<DPP_X8>(s16_3);
            v2f p[16];
#pragma unroll
            for (int j = 0; j < 8; ++j) {                 // +f1 (x2), +f0 (y-elem)
                const float t0 = s8[j];
                const float t1 = dppf<DPP_X2>(t0);
                v2f pa, pb;
                pa.x = t0;  pa.y = dppf<DPP_X1>(t0);
                pb.x = t1;  pb.y = dppf<DPP_X1>(t1);
                p[2 * j]     = pa;
                p[2 * j + 1] = pb;
            }

            // ---- dot(W_row, h) via packed fp32 ----
            v2f a0; a0.x = xp; a0.y = 0.0f;
            a0 = __builtin_elementwise_fma(w2[0], p[0], a0);
            v2f a1 = w2[1] * p[1];
            v2f a2 = w2[2] * p[2];
            v2f a3 = w2[3] * p[3];
#pragma unroll
            for (int k = 1; k < 4; ++k) {
                a0 = __builtin_elementwise_fma(w2[4 * k + 0], p[4 * k + 0], a0);
                a1 = __builtin_elementwise_fma(w2[4 * k + 1], p[4 * k + 1], a1);
                a2 = __builtin_elementwise_fma(w2[4 * k + 2], p[4 * k + 2], a2);
                a3 = __builtin_elementwise_fma(w2[4 * k + 3], p[4 * k + 3], a3);
            }
            const v2f s01 = a0 + a1;
            const v2f s23 = a2 + a3;
            const v2f ss  = s01 + s23;
            const float y = ss.x + ss.y;
            // tanh(y) = 1 - 2/(exp(2y)+1)
            const float e  = __builtin_amdgcn_exp2f(y * 2.8853900817779268f);
            const float rc = __builtin_amdgcn_rcpf(e + 1.0f);
            hn = __builtin_fmaf(-2.0f, rc, 1.0f);
        }
        if (more) xw[h] = xn;                        // install prefetched x chunk
    }

    // out[b] = sum_h h_T[h]*fc_w[h] + fc_b ; butterfly over h-bit distances only
    float v = hn * fc_w[h];
    v += __shfl_xor(v, 1, 64);
    v += __shfl_xor(v, 2, 64);
    v += __shfl_xor(v, 8, 64);
    v += __shfl_xor(v, 16, 64);
    v += __shfl_xor(v, 32, 64);
    if ((lane & 59) == 0) out[b] = v + fc_b[0];      // lanes 0 (sub0) and 4 (sub1)
}

extern "C" void kernel_launch(void* const* d_in, const int* in_sizes, int n_in,
                              void* d_out, int out_size, void* d_ws, size_t ws_size,
                              hipStream_t stream) {
    const float* x    = (const float*)d_in[0];
    const float* W_ih = (const float*)d_in[1];
    const float* W_hh = (const float*)d_in[2];
    const float* b_ih = (const float*)d_in[3];
    const float* b_hh = (const float*)d_in[4];
    const float* fc_w = (const float*)d_in[5];
    const float* fc_b = (const float*)d_in[6];
    float* out = (float*)d_out;

    const int B = out_size;            // 4096
    dim3 grid(B / 8), block(256);      // 8 batch elements per 256-thread block
    hipLaunchKernelGGL(rnn_fused, grid, block, 0, stream,
                       x, W_ih, W_hh, b_ih, b_hh, fc_w, fc_b, out);
}

// Round 7
// 95.554 us; speedup vs baseline: 1.7582x; 1.7582x over previous
//
#include <hip/hip_runtime.h>

#define T_LEN 512

// DPP self-permute: dst[lane] = src[perm(lane)] — all lanes active (proven r6).
template <int CTRL>
__device__ __forceinline__ float dppf(float v) {
    return __int_as_float(__builtin_amdgcn_update_dpp(
        __float_as_int(v), __float_as_int(v), CTRL, 0xF, 0xF, false));
}
#define DPP_X1 0xB1   // quad_perm [1,0,3,2] : lane^1 (exact)
#define DPP_X2 0x4E   // quad_perm [2,3,0,1] : lane^2 (exact)
#define DPP_X8 0x128  // row_ror:8          : lane^8 (exact, proven r6)

// ds_swizzle BitMode xor-exchange within 32-lane groups: j = (i&31)^XORM.
// XOR is an involution -> direction-proof. offset = (xor<<10)|0x1F.
template <int OFF>
__device__ __forceinline__ float swzf(float v) {
    return __int_as_float(__builtin_amdgcn_ds_swizzle(__float_as_int(v), OFF));
}

// One wave = 2 batch elements (sub = lane bit 5), unit h = lane&31.
// Recurrence state hn is register-resident. Per step, only the 4 base values
// hn^{0,4,16,20} are physically gathered (3 parallel ds_swizzle XORs); the
// remaining slot dimension r in {0,1,2,3,8,9,10,11} is absorbed algebraically:
//   y(l) = sum_r Q_r(l^r),  Q_r(j) = sum_m W[h^r][h^m] * hn(j^m)
// so each lane computes 8 four-term partials with pre-gathered weights
// w[r][m] = W_hh[h^r][h^m], then a 3-level DPP combine tree (^1,^2,^8 exact).
// No LDS h-buffer (r4's 240cyc roundtrip + DS-pipe pressure gone); no vector
// packing (r6's ~60 shuffle-mov bloat gone).
__global__ void __launch_bounds__(256) __attribute__((amdgpu_waves_per_eu(2, 2)))
rnn_fused(
    const float* __restrict__ x,
    const float* __restrict__ W_ih,
    const float* __restrict__ W_hh,
    const float* __restrict__ b_ih,
    const float* __restrict__ b_hh,
    const float* __restrict__ fc_w,
    const float* __restrict__ fc_b,
    float* __restrict__ out)
{
    __shared__ __align__(16) float xbuf[4][2][34];  // x chunk broadcast (off critical path)

    const int tid  = threadIdx.x;
    const int wv   = tid >> 6;
    const int lane = tid & 63;
    const int sub  = lane >> 5;      // batch within wave
    const int h    = lane & 31;      // hidden unit owned by this lane
    const int b    = (blockIdx.x << 3) + (wv << 1) + sub;

    // w[ri][mi] = W_hh[h^r][h^m], r=(ri&3)|((ri&4)<<1) in {0..3,8..11},
    //             m=((mi&1)<<2)|((mi>>1)<<4) in {0,4,16,20}. One-time gather.
    float w[8][4];
#pragma unroll
    for (int ri = 0; ri < 8; ++ri) {
        const int r = (ri & 3) | ((ri & 4) << 1);
        const float* row = W_hh + (h ^ r) * 32;
#pragma unroll
        for (int mi = 0; mi < 4; ++mi) {
            const int m = ((mi & 1) << 2) | ((mi >> 1) << 4);
            w[ri][mi] = row[h ^ m];
        }
    }

    const float wih  = W_ih[h];
    const float bias = b_ih[h] + b_hh[h];
    const float* xrow = x + (size_t)b * T_LEN;

    float* xw = &xbuf[wv][sub][0];
    xw[h] = xrow[h];            // stage x chunk 0

    float hn = 0.0f;            // register-resident recurrence state
#pragma unroll 1
    for (int c = 0; c < T_LEN / 32; ++c) {
        // anti-AGPR insurance (emits nothing when weights stay in arch VGPRs)
        asm volatile("" : "+v"(w[0][0]), "+v"(w[0][1]), "+v"(w[0][2]), "+v"(w[0][3]),
                          "+v"(w[1][0]), "+v"(w[1][1]), "+v"(w[1][2]), "+v"(w[1][3]),
                          "+v"(w[2][0]), "+v"(w[2][1]), "+v"(w[2][2]), "+v"(w[2][3]),
                          "+v"(w[3][0]), "+v"(w[3][1]), "+v"(w[3][2]), "+v"(w[3][3]));
        asm volatile("" : "+v"(w[4][0]), "+v"(w[4][1]), "+v"(w[4][2]), "+v"(w[4][3]),
                          "+v"(w[5][0]), "+v"(w[5][1]), "+v"(w[5][2]), "+v"(w[5][3]),
                          "+v"(w[6][0]), "+v"(w[6][1]), "+v"(w[6][2]), "+v"(w[6][3]),
                          "+v"(w[7][0]), "+v"(w[7][1]), "+v"(w[7][2]), "+v"(w[7][3]));
        float xn = 0.0f;
        const bool more = (c < T_LEN / 32 - 1);
        if (more) xn = xrow[(c + 1) * 32 + h];       // prefetch next x chunk
#pragma unroll
        for (int tc = 0; tc < 32; ++tc) {
            const float xt = xw[tc];                 // per-sub uniform broadcast read
            const float xp = __builtin_fmaf(xt, wih, bias);

            // 4 base values, all parallel off hn (one DS latency, bank-perm free)
            const float b0 = hn;
            const float b1 = swzf<0x101F>(hn);       // ^4
            const float b2 = swzf<0x401F>(hn);       // ^16
            const float b3 = swzf<0x501F>(hn);       // ^20

            // 8 four-term partials (independent FMA chains, depth 4)
            float Q[8];
#pragma unroll
            for (int ri = 0; ri < 8; ++ri) {
                float q = w[ri][0] * b0;
                q = __builtin_fmaf(w[ri][1], b1, q);
                q = __builtin_fmaf(w[ri][2], b2, q);
                q = __builtin_fmaf(w[ri][3], b3, q);
                Q[ri] = q;
            }

            // combine tree: y(l) = sum_r Q_r(l^r) over r in {0,1,2,3,8,9,10,11}
            const float A0  = Q[0] + dppf<DPP_X1>(Q[1]);   // r=0,1
            const float A2  = Q[2] + dppf<DPP_X1>(Q[3]);   // r=2,3
            const float A8  = Q[4] + dppf<DPP_X1>(Q[5]);   // r=8,9
            const float A10 = Q[6] + dppf<DPP_X1>(Q[7]);   // r=10,11
            const float B0  = A0 + dppf<DPP_X2>(A2);
            const float B8  = A8 + dppf<DPP_X2>(A10);
            const float y   = (xp + B0) + dppf<DPP_X8>(B8);

            // tanh(y) = 1 - 2/(exp(2y)+1)
            const float e  = __builtin_amdgcn_exp2f(y * 2.8853900817779268f);
            const float rc = __builtin_amdgcn_rcpf(e + 1.0f);
            hn = __builtin_fmaf(-2.0f, rc, 1.0f);
        }
        if (more) xw[h] = xn;                        // install prefetched x chunk
    }

    // out[b] = sum_h h_T[h]*fc_w[h] + fc_b ; butterfly within each 32-lane half
    float v = hn * fc_w[h];
#pragma unroll
    for (int m = 16; m >= 1; m >>= 1) v += __shfl_xor(v, m, 64);
    if (h == 0) out[b] = v + fc_b[0];
}

extern "C" void kernel_launch(void* const* d_in, const int* in_sizes, int n_in,
                              void* d_out, int out_size, void* d_ws, size_t ws_size,
                              hipStream_t stream) {
    const float* x    = (const float*)d_in[0];
    const float* W_ih = (const float*)d_in[1];
    const float* W_hh = (const float*)d_in[2];
    const float* b_ih = (const float*)d_in[3];
    const float* b_hh = (const float*)d_in[4];
    const float* fc_w = (const float*)d_in[5];
    const float* fc_b = (const float*)d_in[6];
    float* out = (float*)d_out;

    const int B = out_size;            // 4096
    dim3 grid(B / 8), block(256);      // 8 batch elements per 256-thread block
    hipLaunchKernelGGL(rnn_fused, grid, block, 0, stream,
                       x, W_ih, W_hh, b_ih, b_hh, fc_w, fc_b, out);
}

// Round 8
// 86.473 us; speedup vs baseline: 1.9428x; 1.1050x over previous
//
#include <hip/hip_runtime.h>

#define T_LEN 512

// DPP self-permute: dst[lane] = src[perm(lane)].
// old=0 + bound_ctrl=1 + full masks: 'old' is dead (all lanes written, all
// sources valid for quad_perm/row_ror) -> no tied-register copy, and the DPP
// mov is foldable into the consuming VALU op (v_add_f32_dpp).
template <int CTRL>
__device__ __forceinline__ float dppf(float v) {
    return __int_as_float(__builtin_amdgcn_update_dpp(
        0, __float_as_int(v), CTRL, 0xF, 0xF, true));
}
#define DPP_X1 0xB1   // quad_perm [1,0,3,2] : lane^1 (exact)
#define DPP_X2 0x4E   // quad_perm [2,3,0,1] : lane^2 (exact)
#define DPP_X8 0x128  // row_ror:8          : lane^8 (exact, proven r6/r7)

// ds_swizzle BitMode xor-exchange within 32-lane groups: j = (i&31)^XORM.
template <int OFF>
__device__ __forceinline__ float swzf(float v) {
    return __int_as_float(__builtin_amdgcn_ds_swizzle(__float_as_int(v), OFF));
}

// One wave = 2 batch elements (sub = lane bit 5), unit h = lane&31.
// Register-resident recurrence; physical gather only of hn^{0,4,16,20}
// (3 parallel ds_swizzle XORs), slot dimension r in {0,1,2,3,8,9,10,11}
// absorbed algebraically:
//   y(l) = sum_r Q_r(l^r),  Q_r(j) = sum_m W[h^r][h^m] * hn(j^m)
// with pre-gathered weights w[r][m] = W_hh[h^r][h^m], then a 3-level DPP
// combine tree (^1,^2,^8). Verified exact in r7 (absmax 0.0).
__global__ void __launch_bounds__(256) __attribute__((amdgpu_waves_per_eu(2, 2)))
rnn_fused(
    const float* __restrict__ x,
    const float* __restrict__ W_ih,
    const float* __restrict__ W_hh,
    const float* __restrict__ b_ih,
    const float* __restrict__ b_hh,
    const float* __restrict__ fc_w,
    const float* __restrict__ fc_b,
    float* __restrict__ out)
{
    __shared__ __align__(16) float xbuf[4][2][34];  // x chunk broadcast (off critical path)

    const int tid  = threadIdx.x;
    const int wv   = tid >> 6;
    const int lane = tid & 63;
    const int sub  = lane >> 5;      // batch within wave
    const int h    = lane & 31;      // hidden unit owned by this lane
    const int b    = (blockIdx.x << 3) + (wv << 1) + sub;

    // w[ri][mi] = W_hh[h^r][h^m], r=(ri&3)|((ri&4)<<1) in {0..3,8..11},
    //             m=((mi&1)<<2)|((mi>>1)<<4) in {0,4,16,20}. One-time gather.
    float w[8][4];
#pragma unroll
    for (int ri = 0; ri < 8; ++ri) {
        const int r = (ri & 3) | ((ri & 4) << 1);
        const float* row = W_hh + (h ^ r) * 32;
#pragma unroll
        for (int mi = 0; mi < 4; ++mi) {
            const int m = ((mi & 1) << 2) | ((mi >> 1) << 4);
            w[ri][mi] = row[h ^ m];
        }
    }

    const float wih  = W_ih[h];
    const float bias = b_ih[h] + b_hh[h];
    const float* xrow = x + (size_t)b * T_LEN;

    float* xw = &xbuf[wv][sub][0];
    xw[h] = xrow[h];            // stage x chunk 0

    float hn = 0.0f;            // register-resident recurrence state
#pragma unroll 1
    for (int c = 0; c < T_LEN / 32; ++c) {
        // anti-AGPR insurance (emits nothing when weights stay in arch VGPRs)
        asm volatile("" : "+v"(w[0][0]), "+v"(w[0][1]), "+v"(w[0][2]), "+v"(w[0][3]),
                          "+v"(w[1][0]), "+v"(w[1][1]), "+v"(w[1][2]), "+v"(w[1][3]),
                          "+v"(w[2][0]), "+v"(w[2][1]), "+v"(w[2][2]), "+v"(w[2][3]),
                          "+v"(w[3][0]), "+v"(w[3][1]), "+v"(w[3][2]), "+v"(w[3][3]));
        asm volatile("" : "+v"(w[4][0]), "+v"(w[4][1]), "+v"(w[4][2]), "+v"(w[4][3]),
                          "+v"(w[5][0]), "+v"(w[5][1]), "+v"(w[5][2]), "+v"(w[5][3]),
                          "+v"(w[6][0]), "+v"(w[6][1]), "+v"(w[6][2]), "+v"(w[6][3]),
                          "+v"(w[7][0]), "+v"(w[7][1]), "+v"(w[7][2]), "+v"(w[7][3]));
        float xn = 0.0f;
        const bool more = (c < T_LEN / 32 - 1);
        if (more) xn = xrow[(c + 1) * 32 + h];       // prefetch next x chunk
#pragma unroll
        for (int tc = 0; tc < 32; ++tc) {
            const float xt = xw[tc];                 // per-sub uniform broadcast read
            const float xp = __builtin_fmaf(xt, wih, bias);

            // 4 base values, all parallel off hn (one DS latency, bank-perm free)
            const float b0 = hn;
            const float b1 = swzf<0x101F>(hn);       // ^4
            const float b2 = swzf<0x401F>(hn);       // ^16
            const float b3 = swzf<0x501F>(hn);       // ^20

            // 8 four-term partials (independent FMA chains, depth 4)
            float Q[8];
#pragma unroll
            for (int ri = 0; ri < 8; ++ri) {
                float q = w[ri][0] * b0;
                q = __builtin_fmaf(w[ri][1], b1, q);
                q = __builtin_fmaf(w[ri][2], b2, q);
                q = __builtin_fmaf(w[ri][3], b3, q);
                Q[ri] = q;
            }

            // combine tree: y(l) = sum_r Q_r(l^r), r in {0,1,2,3,8,9,10,11}
            const float A0  = Q[0] + dppf<DPP_X1>(Q[1]);   // r=0,1
            const float A2  = Q[2] + dppf<DPP_X1>(Q[3]);   // r=2,3
            const float A8  = Q[4] + dppf<DPP_X1>(Q[5]);   // r=8,9
            const float A10 = Q[6] + dppf<DPP_X1>(Q[7]);   // r=10,11
            const float B0  = A0 + dppf<DPP_X2>(A2);
            const float B8  = A8 + dppf<DPP_X2>(A10);
            const float y   = (xp + B0) + dppf<DPP_X8>(B8);

            // tanh(y) = 1 - 2/(exp(2y)+1)
            const float e  = __builtin_amdgcn_exp2f(y * 2.8853900817779268f);
            const float rc = __builtin_amdgcn_rcpf(e + 1.0f);
            hn = __builtin_fmaf(-2.0f, rc, 1.0f);
        }
        if (more) xw[h] = xn;                        // install prefetched x chunk
    }

    // out[b] = sum_h h_T[h]*fc_w[h] + fc_b ; butterfly within each 32-lane half
    float v = hn * fc_w[h];
#pragma unroll
    for (int m = 16; m >= 1; m >>= 1) v += __shfl_xor(v, m, 64);
    if (h == 0) out[b] = v + fc_b[0];
}

extern "C" void kernel_launch(void* const* d_in, const int* in_sizes, int n_in,
                              void* d_out, int out_size, void* d_ws, size_t ws_size,
                              hipStream_t stream) {
    const float* x    = (const float*)d_in[0];
    const float* W_ih = (const float*)d_in[1];
    const float* W_hh = (const float*)d_in[2];
    const float* b_ih = (const float*)d_in[3];
    const float* b_hh = (const float*)d_in[4];
    const float* fc_w = (const float*)d_in[5];
    const float* fc_b = (const float*)d_in[6];
    float* out = (float*)d_out;

    const int B = out_size;            // 4096
    dim3 grid(B / 8), block(256);      // 8 batch elements per 256-thread block
    hipLaunchKernelGGL(rnn_fused, grid, block, 0, stream,
                       x, W_ih, W_hh, b_ih, b_hh, fc_w, fc_b, out);
}